// Round 25
// baseline (231.202 us; speedup 1.0000x reference)
//
#include <hip/hip_runtime.h>
#include <stdint.h>

typedef uint16_t u16;
typedef uint32_t u32;
typedef uint64_t u64;

#define CONF_THRESH 0.5f
#define PIOU_THRESH 0.5f
#define NBIN 64      // fixed-width spatial bins (width 79.7; box width < 95 -> edges span <=1 bin)
#define NWAVE 8      // nms waves: 0=decide, 1-5=far gather, 6=near stage, 7=meta stage
#define FCAP 8192    // far-edge slots per TARGET chunk (avg ~2500; 3.3x margin)
#define NCAP 2048    // near-edge slots per SOURCE chunk (avg ~40; 50x margin)
#define NBKT 2048    // conf-bit buckets for counting rank
#define BCAP 64      // members per bucket (lambda~4; P(overflow) ~ 1e-60; writes guarded)
#define GQ 7         // max quad-iterations per gather wave (FCAP/256/5 rounded up)

// ---------------------------------------------------------------------------
// K1: bucket histogram + member-key lists + aux zeroing (proven R16-R24).
// cnt[0..127]=far counts (by target chunk), cnt[128..255]=near counts (by
// source chunk). Multi-block all-CU shape (R20 lesson).
// ---------------------------------------------------------------------------
__global__ void __launch_bounds__(256) hist_kernel(
        const float* __restrict__ in, u32* __restrict__ hist, u64* __restrict__ mem,
        u32* __restrict__ meta, u32* __restrict__ cnt, u32* __restrict__ bcnt,
        u16* __restrict__ grankg, int N) {
    int i = blockIdx.x * 256 + threadIdx.x;      // N threads total
    for (int q = i; q < 4 * N; q += N) meta[q] = 0u;
    if (i < 256) cnt[i] = 0u;
    if (i < NBIN) bcnt[i] = 0u;
    u32* g32 = (u32*)grankg;
    if (i < N / 2) g32[i] = 0u;                  // grankg = all 0 (empty sentinel)
    if (i >= N) return;
    float c = in[(size_t)i * 5];
    if (c > CONF_THRESH) {
        u32 bits = __float_as_uint(c);
        int b = (int)((bits - 0x3F000000u) >> 12);   // 0..2047 (monotone in conf)
        u32 s = atomicAdd(&hist[b], 1u);
        if (s < BCAP)
            mem[(size_t)b * BCAP + s] = ((u64)bits << 32) | (u64)(0xFFFFFFFFu - (u32)i);
    }
}

// ---------------------------------------------------------------------------
// K2: exact rank from buckets -> scatter (verbatim proven R16-R24).
// ---------------------------------------------------------------------------
__global__ void __launch_bounds__(256) rankscat_kernel(
        const float* __restrict__ in, const u32* __restrict__ hist,
        const u64* __restrict__ mem, float4* __restrict__ sbox,
        u32* __restrict__ bcnt, u16* __restrict__ grankg,
        float4* __restrict__ sboxg, int N) {
    __shared__ u32 h[NBKT];
    __shared__ u32 base[NBKT];
    __shared__ u32 p[256];
    int t = threadIdx.x;
    for (int k = t; k < NBKT; k += 256) h[k] = hist[k];
    __syncthreads();
    u32 hv[8]; u32 seg = 0;
    for (int j = 0; j < 8; ++j) { hv[j] = h[t * 8 + j]; seg += hv[j]; }
    p[t] = seg;
    __syncthreads();
    u32 sp = 0;
    for (int q = t + 1; q < 256; ++q) sp += p[q];    // suffix over segments
    u32 run = sp;
    for (int j = 7; j >= 0; --j) { base[t * 8 + j] = run; run += hv[j]; }
    __syncthreads();

    int i = blockIdx.x * 256 + t;
    float c = in[(size_t)i * 5];
    if (c <= CONF_THRESH) return;                // no syncs follow
    u32 bits = __float_as_uint(c);
    int b = (int)((bits - 0x3F000000u) >> 12);
    u64 my = ((u64)bits << 32) | (u64)(0xFFFFFFFFu - (u32)i);
    int n = min((int)h[b], BCAP);
    const u64* mb = mem + (size_t)b * BCAP;
    int cnt2 = 0;
    for (int e = 0; e < n; ++e) cnt2 += (mb[e] > my) ? 1 : 0;
    int r = (int)base[b] + cnt2;

    const float* pp = in + (size_t)i * 5;
    float4 bx = make_float4(pp[1], pp[2], pp[3], pp[4]);
    sbox[r] = bx;
    int bin = min(NBIN - 1, max(0, (int)(bx.x * ((float)NBIN / 5100.0f))));
    u32 slot = atomicAdd(&bcnt[bin], 1u);
    if (slot < 256) {
        int g = bin * 256 + (int)slot;
        grankg[g] = (u16)(r + 1);                // r+1 encoding; 0 = empty
        sboxg[g] = bx;
    }
}

// ---------------------------------------------------------------------------
// K3: suppression edges, +-1-bin window (verbatim proven R23/R24 routing):
// d = (rj>>7)-(ri>>7): d==0 -> meta bit; d==1 -> near list of SOURCE chunk,
// (sl<<16)|(rj&127); d>=2 -> far list of TARGET chunk, (ri<<7)|(rj&127).
// ---------------------------------------------------------------------------
__global__ void mask_pm1_kernel(const float4* __restrict__ sboxg, const u16* __restrict__ grankg,
                                const u32* __restrict__ bcnt,
                                u32* __restrict__ meta, u32* __restrict__ fare,
                                u32* __restrict__ neare, u32* __restrict__ cnt) {
#pragma clang fp contract(off)
    __shared__ float4 cb[192];
    __shared__ u16 cr[192];
    int b = (int)blockIdx.x, s = (int)blockIdx.y, t = threadIdx.x;
    int w0 = (b - 1) * 256 + s * 192;            // window slice start (gidx)
    if (t < 192) {
        int g = w0 + t;
        bool ok = (g >= 0) && (g < NBIN * 256);
        cr[t] = ok ? grankg[g] : (u16)0;         // 0 = empty sentinel
        cb[t] = ok ? sboxg[g] : make_float4(0.0f, 0.0f, 0.0f, 0.0f);
    }
    __syncthreads();
    int nb = min((int)bcnt[b], 256);
    int l = t;
    if (l >= nb) return;
    int g = b * 256 + l;
    int rj = (int)grankg[g] - 1;                 // filled slot: >= 0
    float4 bj = sboxg[g];
    float areaj = (bj.y - bj.x) * bj.w;
    for (int q = 0; q < 192; ++q) {
        int rie = (int)cr[q];
        if (rie == 0) continue;                  // empty slot
        int ri = rie - 1;
        if (ri >= rj) continue;                  // keeps only higher-conf suppressors
        float4 bi = cb[q];
        float inter_start = fmaxf(bi.x, bj.x);
        float inter_end   = fminf(bi.y, bj.y);
        float inter_len   = fmaxf(inter_end - inter_start, 0.0f);
        float inter_h     = fminf(bi.w, bj.w);
        float inter_area  = inter_len * inter_h;
        float areai       = (bi.y - bi.x) * bi.w;
        float union_area  = areai + areaj - inter_area;
        float iou         = inter_area / union_area;
        float peak_dist   = fabsf(bi.z - bj.z);
        float union_start = fminf(bi.x, bj.x);
        float union_end   = fmaxf(bi.y, bj.y);
        float union_dist  = fabsf(union_end - union_start);
        float piou        = iou - peak_dist / union_dist;
        if (piou > PIOU_THRESH) {
            int d = (rj >> 7) - (ri >> 7);
            if (d == 0) {
                atomicOr(&meta[rj * 4 + ((ri >> 5) & 3)], 1u << (ri & 31));
            } else if (d == 1) {
                int c = ri >> 7;
                u32 slot = atomicAdd(&cnt[128 + c], 1u);
                if (slot < NCAP)
                    neare[(size_t)c * NCAP + slot] = ((u32)(ri & 127) << 16) | (u32)(rj & 127);
            } else {
                int c = rj >> 7;
                u32 slot = atomicAdd(&cnt[c], 1u);
                if (slot < FCAP)
                    fare[(size_t)c * FCAP + slot] = ((u32)ri << 7) | (u32)(rj & 127);
            }
        }
    }
}

// ---------------------------------------------------------------------------
// K4: EXACT greedy NMS, parallel-gather schedule (proven R23/R24) + R25
// CHANGE: gather waves accumulate hits into REGISTERS (branchless 4-word
// select), wave-OR-reduce via 6-level shfl_xor, then lane 0 issues 4
// atomicOrs -- cutting same-address LDS atomics from ~1000/step to ~20/step
// (the R23/R24-invariant ~2400cy step cost attributed to atomic
// serialization; bank-conflict counter ~2950 is the fingerprint).
// All else verbatim R24 (batched loads kept).
// ---------------------------------------------------------------------------
__global__ void __launch_bounds__(NWAVE * 64) nmsout_kernel(
        const u32* __restrict__ bcnt, const u32* __restrict__ meta,
        const u32* __restrict__ fare, const u32* __restrict__ neare,
        const u32* __restrict__ cnt, const float4* __restrict__ sbox,
        float4* __restrict__ out, int N) {
    __shared__ u32 alive[512];                   // 16384 bits, rank space
    __shared__ u32 supp[130][4];                 // per-chunk suppressed accumulators
    __shared__ u32 metb[2][512];                 // staged meta (128 ranks x 4 u32)
    __shared__ u32 nearb[2][NCAP];               // staged near edges (8 KB each)
    __shared__ u32 ncnt_s[2];
    __shared__ u32 mcnt;
    int tid = threadIdx.x;
    int w = tid >> 6, lane = tid & 63;

    // ---- M = sum over bins of (uncapped) valid counts ----
    if (tid < 64) {
        int lc = (int)bcnt[lane];
        lc += __shfl_xor(lc, 1);  lc += __shfl_xor(lc, 2);
        lc += __shfl_xor(lc, 4);  lc += __shfl_xor(lc, 8);
        lc += __shfl_xor(lc, 16); lc += __shfl_xor(lc, 32);
        if (lane == 0) mcnt = (u32)lc;
    }
    for (int q = tid; q < 130 * 4; q += NWAVE * 64) ((u32*)supp)[q] = 0u;
    __syncthreads();
    int M = (int)mcnt;
    {
        int lo = tid * 32;
        alive[tid] = (M >= lo + 32) ? 0xFFFFFFFFu : ((M <= lo) ? 0u : ((1u << (M - lo)) - 1u));
    }
    int nchunk = (M + 127) >> 7;                 // 128-rank chunks
    __syncthreads();

    // ---- prologue: stage chunk 0's meta + near into buffer 0 ----
    if (nchunk > 0) {
        if (w == 7) {
            uint4 M0 = ((const uint4*)meta)[lane];
            uint4 M1 = ((const uint4*)meta)[64 + lane];
            ((uint4*)metb[0])[lane] = M0;
            ((uint4*)metb[0])[64 + lane] = M1;
        } else if (w == 6) {
            int nc2 = min((int)cnt[128], NCAP);
            if (lane == 0) ncnt_s[0] = (u32)nc2;
            const uint4* nq = (const uint4*)neare;
            uint4* nd = (uint4*)nearb[0];
            for (int qi = 0; qi * 256 < nc2; ++qi) nd[qi * 64 + lane] = nq[qi * 64 + lane];
        }
    }
    __syncthreads();

#define FAR_E(e, idx) { \
    if ((int)(idx) < fc) { \
        u32 ri = (e) >> 7, tg = (e) & 127; \
        if ((alive[ri >> 5] >> (ri & 31)) & 1u) { \
            u32 bit = 1u << (tg & 31); u32 wi = tg >> 5; \
            a0 |= (wi == 0) ? bit : 0u; \
            a1 |= (wi == 1) ? bit : 0u; \
            a2 |= (wi == 2) ? bit : 0u; \
            a3 |= (wi == 3) ? bit : 0u; } } }

#define NEAR_E(e, idx) { \
    if ((int)(idx) < ne) { \
        u32 sl = (e) >> 16, tg = (e) & 127; \
        u64 ksel = (sl & 64) ? kept_hi : kept_lo; \
        if ((ksel >> (sl & 63)) & 1ull) \
            atomicOr(&supp[c + 1][tg >> 5], 1u << (tg & 31)); } }

    for (int c = 0; c < nchunk; ++c) {
        int pb = c & 1;
        if (w == 0) {
            // ---- decide chunk c ----
            int base = c << 7;
            uint4 MT0 = ((const uint4*)metb[pb])[lane];
            uint4 MT1 = ((const uint4*)metb[pb])[64 + lane];
            uint4 S = *(const uint4*)&supp[c][0];            // wave-uniform
            u64 sup_lo = (u64)S.x | ((u64)S.y << 32);
            u64 sup_hi = (u64)S.z | ((u64)S.w << 32);
            u64 av_lo = (((u64)alive[(base >> 5) + 1] << 32) | (u64)alive[base >> 5]) & ~sup_lo;
            u64 av_hi = (((u64)alive[(base >> 5) + 3] << 32) | (u64)alive[(base >> 5) + 2]) & ~sup_hi;
            u64 kept_lo, kept_hi;
            u32 anym = MT0.x | MT0.y | MT0.z | MT0.w | MT1.x | MT1.y | MT1.z | MT1.w;
            if (__ballot(anym != 0u) == 0ull) {
                kept_lo = av_lo; kept_hi = av_hi;            // no in-chunk deps (common)
            } else {
                u64 m0_lo = MT0.x | ((u64)MT0.y << 32), m0_hi = MT0.z | ((u64)MT0.w << 32);
                u64 m1_lo = MT1.x | ((u64)MT1.y << 32), m1_hi = MT1.z | ((u64)MT1.w << 32);
                u64 undec_lo = av_lo, undec_hi = av_hi;
                kept_lo = 0ull; kept_hi = 0ull;
                while (undec_lo | undec_hi) {
                    bool iam0 = (undec_lo >> lane) & 1ull;
                    bool bad0 = ((m0_lo & kept_lo) | (m0_hi & kept_hi)) != 0ull;
                    bool rdy0 = ((m0_lo & undec_lo) | (m0_hi & undec_hi)) == 0ull;
                    bool iam1 = (undec_hi >> lane) & 1ull;
                    bool bad1 = ((m1_lo & kept_lo) | (m1_hi & kept_hi)) != 0ull;
                    bool rdy1 = ((m1_lo & undec_lo) | (m1_hi & undec_hi)) == 0ull;
                    u64 nk_lo = __ballot(iam0 && !bad0 && rdy0);
                    u64 nr_lo = __ballot(iam0 && bad0);
                    u64 nk_hi = __ballot(iam1 && !bad1 && rdy1);
                    u64 nr_hi = __ballot(iam1 && bad1);
                    u64 pl = nk_lo | nr_lo, ph = nk_hi | nr_hi;
                    if ((pl | ph) == 0ull) {                 // hang insurance (dead on valid data)
                        if (undec_lo) { pl = undec_lo & (~undec_lo + 1ull); nk_lo = pl; }
                        else          { ph = undec_hi & (~undec_hi + 1ull); nk_hi = ph; }
                    }
                    kept_lo |= nk_lo; kept_hi |= nk_hi;
                    undec_lo &= ~pl;  undec_hi &= ~ph;
                }
            }
            if (lane < 4) {
                u32 word = (lane == 0) ? (u32)kept_lo :
                           (lane == 1) ? (u32)(kept_lo >> 32) :
                           (lane == 2) ? (u32)kept_hi : (u32)(kept_hi >> 32);
                alive[(base >> 5) + lane] = word;
            }
            // ---- scatter near edges of c into supp[c+1] (small list) ----
            int ne = (int)ncnt_s[pb];
            const uint4* nd = (const uint4*)nearb[pb];
            for (int qi = 0; qi * 256 < ne; ++qi) {
                uint4 E = nd[qi * 64 + lane];
                int e0 = qi * 256 + lane * 4;
                NEAR_E(E.x, e0)     NEAR_E(E.y, e0 + 1)
                NEAR_E(E.z, e0 + 2) NEAR_E(E.w, e0 + 3)
            }
        } else if (w <= 5) {
            // ---- gather far in-edges of chunk c+1: batched loads (R24) +
            //      register accumulate / wave-reduce / 4 atomics (R25) ----
            int tc = c + 1;
            if (tc < nchunk) {
                int fc = min((int)cnt[tc], FCAP);
                int nq = (fc + 255) >> 8;                    // quad batches total
                const uint4* fq = (const uint4*)(fare + (size_t)tc * FCAP);
                uint4 EB[GQ];
#pragma unroll
                for (int u = 0; u < GQ; ++u) {               // issue all loads first
                    int qi = (w - 1) + u * 5;
                    EB[u] = (qi < nq) ? fq[qi * 64 + lane] : make_uint4(0u, 0u, 0u, 0u);
                }
                u32 a0 = 0u, a1 = 0u, a2 = 0u, a3 = 0u;
#pragma unroll
                for (int u = 0; u < GQ; ++u) {               // then accumulate
                    int qi = (w - 1) + u * 5;
                    if (qi < nq) {
                        uint4 E = EB[u];
                        int e0 = qi * 256 + lane * 4;
                        FAR_E(E.x, e0)     FAR_E(E.y, e0 + 1)
                        FAR_E(E.z, e0 + 2) FAR_E(E.w, e0 + 3)
                    }
                }
#pragma unroll
                for (int off = 1; off < 64; off <<= 1) {     // wave OR-reduce
                    a0 |= __shfl_xor(a0, off);
                    a1 |= __shfl_xor(a1, off);
                    a2 |= __shfl_xor(a2, off);
                    a3 |= __shfl_xor(a3, off);
                }
                if (lane == 0) {
                    if (a0) atomicOr(&supp[tc][0], a0);
                    if (a1) atomicOr(&supp[tc][1], a1);
                    if (a2) atomicOr(&supp[tc][2], a2);
                    if (a3) atomicOr(&supp[tc][3], a3);
                }
            }
        } else if (w == 6) {
            // ---- stage near list of chunk c+1 ----
            int sc = c + 1;
            if (sc < nchunk) {
                int nc2 = min((int)cnt[128 + sc], NCAP);
                if (lane == 0) ncnt_s[pb ^ 1] = (u32)nc2;
                const uint4* nq = (const uint4*)(neare + (size_t)sc * NCAP);
                uint4* nd = (uint4*)nearb[pb ^ 1];
                for (int qi = 0; qi * 256 < nc2; ++qi) nd[qi * 64 + lane] = nq[qi * 64 + lane];
            } else if (lane == 0) ncnt_s[pb ^ 1] = 0u;
        } else {
            // ---- w == 7: stage meta of chunk c+1 ----
            int sc = c + 1;
            if (sc < nchunk) {
                int rr = (sc << 7) + lane;
                uint4 M0 = ((const uint4*)meta)[rr];
                uint4 M1 = ((const uint4*)meta)[rr + 64];
                ((uint4*)metb[pb ^ 1])[lane] = M0;
                ((uint4*)metb[pb ^ 1])[64 + lane] = M1;
            }
        }
        __syncthreads();                         // step boundary (uniform)
    }

    // fused output: all 8 waves stream the result (alive is final)
    for (int r = tid; r < N; r += NWAVE * 64) {
        if (r < M) {
            float kf = (float)((alive[r >> 5] >> (r & 31)) & 1u);
            float4 v = sbox[r];
            out[r] = make_float4(v.x * kf, v.y * kf, v.z * kf, v.w * kf);
        } else {
            out[r] = make_float4(0.0f, 0.0f, 0.0f, 0.0f);
        }
    }
#undef FAR_E
#undef NEAR_E
}

// ---------------------------------------------------------------------------
extern "C" void kernel_launch(void* const* d_in, const int* in_sizes, int n_in,
                              void* d_out, int out_size, void* d_ws, size_t ws_size,
                              hipStream_t stream) {
    const float* in = (const float*)d_in[0];
    int N = in_sizes[0] / 5;          // 16384
    int nchunk_max = N / 128;         // 128

    char* ws = (char*)d_ws;
    size_t off = 0;
    u32* hist    = (u32*)(ws + off); off += (size_t)NBKT * 4;         // 8 KB (memset'd)
    u32* bcnt    = (u32*)(ws + off); off += (size_t)NBIN * 4;         // 256 B
    u32* cnt     = (u32*)(ws + off); off += 256 * 4;                  // 1 KB (far+near counts)
    u16* grankg  = (u16*)(ws + off); off += (size_t)N * 2;            // 32 KB
    off = (off + 15) & ~(size_t)15;
    u32* meta    = (u32*)(ws + off); off += (size_t)N * 16;           // 256 KB
    u64* mem     = (u64*)(ws + off); off += (size_t)NBKT * BCAP * 8;  // 1 MB
    float4* sbox  = (float4*)(ws + off); off += (size_t)N * 16;       // 256 KB
    float4* sboxg = (float4*)(ws + off); off += (size_t)N * 16;       // 256 KB
    u32* fare    = (u32*)(ws + off);  off += (size_t)nchunk_max * FCAP * 4;  // 4 MB
    u32* neare   = (u32*)(ws + off);  off += (size_t)nchunk_max * NCAP * 4;  // 1 MB

    hipMemsetAsync(hist, 0, (size_t)NBKT * 4, stream);

    hist_kernel<<<N / 256, 256, 0, stream>>>(in, hist, mem, meta, cnt, bcnt, grankg, N);
    rankscat_kernel<<<N / 256, 256, 0, stream>>>(in, hist, mem, sbox, bcnt, grankg, sboxg, N);
    mask_pm1_kernel<<<dim3(NBIN, 4), 256, 0, stream>>>(sboxg, grankg, bcnt, meta, fare, neare, cnt);
    nmsout_kernel<<<1, NWAVE * 64, 0, stream>>>(bcnt, meta, fare, neare, cnt, sbox, (float4*)d_out, N);
}

// Round 26
// 184.293 us; speedup vs baseline: 1.2545x; 1.2545x over previous
//
#include <hip/hip_runtime.h>
#include <stdint.h>

typedef uint16_t u16;
typedef uint32_t u32;
typedef uint64_t u64;

#define CONF_THRESH 0.5f
#define PIOU_THRESH 0.5f
#define NBIN 64      // fixed-width spatial bins (width 79.7; box width < 95 -> edges span <=1 bin)
#define NWAVE 8      // nms waves: wave 0 consumes, waves 1-7 stage
#define CPR 4        // chunks per round (chunks are 128 ranks wide)
#define ECAP_CHUNK 12288 // edge slots per 128-chunk (2x R9's 6144: same margin per rank)
#define ESTG 3584    // edges staged in LDS per chunk (2x R15's 1792: same per-rank capacity)
#define CHW 4096     // u32 per chunk buffer: 512 meta (128 ranks x 4) + 3584 staged edges (16 KB)
#define NBKT 2048    // conf-bit buckets for counting rank
#define BCAP 64      // members per bucket (lambda~4; P(overflow) ~ 1e-60; writes guarded)

// ---------------------------------------------------------------------------
// K1: bucket histogram + member-key lists + aux zeroing (proven R16-R22).
// Multi-block all-CU shape (R20's 1-block variant slowed downstream by ~15us).
// ---------------------------------------------------------------------------
__global__ void __launch_bounds__(256) hist_kernel(
        const float* __restrict__ in, u32* __restrict__ hist, u64* __restrict__ mem,
        u32* __restrict__ meta, u32* __restrict__ echnk, u32* __restrict__ bcnt,
        u16* __restrict__ grankg, int N) {
    int i = blockIdx.x * 256 + threadIdx.x;      // N threads total
    for (int q = i; q < 4 * N; q += N) meta[q] = 0u;
    if (i < 256) echnk[i] = 0u;                  // covers 128 chunks
    if (i < NBIN) bcnt[i] = 0u;
    u32* g32 = (u32*)grankg;
    if (i < N / 2) g32[i] = 0u;                  // grankg = all 0 (empty sentinel)
    if (i >= N) return;
    float c = in[(size_t)i * 5];
    if (c > CONF_THRESH) {
        u32 bits = __float_as_uint(c);
        int b = (int)((bits - 0x3F000000u) >> 12);   // 0..2047 (monotone in conf)
        u32 s = atomicAdd(&hist[b], 1u);
        if (s < BCAP)
            mem[(size_t)b * BCAP + s] = ((u64)bits << 32) | (u64)(0xFFFFFFFFu - (u32)i);
    }
}

// ---------------------------------------------------------------------------
// K2: exact rank from buckets -> scatter (verbatim proven R16-R22).
// ---------------------------------------------------------------------------
__global__ void __launch_bounds__(256) rankscat_kernel(
        const float* __restrict__ in, const u32* __restrict__ hist,
        const u64* __restrict__ mem, float4* __restrict__ sbox,
        u32* __restrict__ bcnt, u16* __restrict__ grankg,
        float4* __restrict__ sboxg, int N) {
    __shared__ u32 h[NBKT];
    __shared__ u32 base[NBKT];
    __shared__ u32 p[256];
    int t = threadIdx.x;
    for (int k = t; k < NBKT; k += 256) h[k] = hist[k];
    __syncthreads();
    u32 hv[8]; u32 seg = 0;
    for (int j = 0; j < 8; ++j) { hv[j] = h[t * 8 + j]; seg += hv[j]; }
    p[t] = seg;
    __syncthreads();
    u32 sp = 0;
    for (int q = t + 1; q < 256; ++q) sp += p[q];    // suffix over segments
    u32 run = sp;
    for (int j = 7; j >= 0; --j) { base[t * 8 + j] = run; run += hv[j]; }
    __syncthreads();

    int i = blockIdx.x * 256 + t;
    float c = in[(size_t)i * 5];
    if (c <= CONF_THRESH) return;                // no syncs follow
    u32 bits = __float_as_uint(c);
    int b = (int)((bits - 0x3F000000u) >> 12);
    u64 my = ((u64)bits << 32) | (u64)(0xFFFFFFFFu - (u32)i);
    int n = min((int)h[b], BCAP);
    const u64* mb = mem + (size_t)b * BCAP;
    int cnt = 0;
    for (int e = 0; e < n; ++e) cnt += (mb[e] > my) ? 1 : 0;
    int r = (int)base[b] + cnt;

    const float* pp = in + (size_t)i * 5;
    float4 bx = make_float4(pp[1], pp[2], pp[3], pp[4]);
    sbox[r] = bx;
    int bin = min(NBIN - 1, max(0, (int)(bx.x * ((float)NBIN / 5100.0f))));
    u32 slot = atomicAdd(&bcnt[bin], 1u);
    if (slot < 256) {
        int g = bin * 256 + (int)slot;
        grankg[g] = (u16)(r + 1);                // r+1 encoding; 0 = empty
        sboxg[g] = bx;
    }
}

// ---------------------------------------------------------------------------
// K3: suppression edges, +-1-bin window (proven R12-R22 math). 128-rank
// chunks: in-chunk = (ri>>7)==(rj>>7), mask bit in meta[rj*4 + (ri>>5)&3];
// cross-chunk edge ((ri&127)<<16)|rj into chunk ri>>7's list.
// ---------------------------------------------------------------------------
__global__ void mask_pm1_kernel(const float4* __restrict__ sboxg, const u16* __restrict__ grankg,
                                const u32* __restrict__ bcnt,
                                u32* __restrict__ meta, u32* __restrict__ edges,
                                u32* __restrict__ echnk) {
#pragma clang fp contract(off)
    __shared__ float4 cb[192];
    __shared__ u16 cr[192];
    int b = (int)blockIdx.x, s = (int)blockIdx.y, t = threadIdx.x;
    int w0 = (b - 1) * 256 + s * 192;            // window slice start (gidx)
    if (t < 192) {
        int g = w0 + t;
        bool ok = (g >= 0) && (g < NBIN * 256);
        cr[t] = ok ? grankg[g] : (u16)0;         // 0 = empty sentinel
        cb[t] = ok ? sboxg[g] : make_float4(0.0f, 0.0f, 0.0f, 0.0f);
    }
    __syncthreads();
    int nb = min((int)bcnt[b], 256);
    int l = t;
    if (l >= nb) return;
    int g = b * 256 + l;
    int rj = (int)grankg[g] - 1;                 // filled slot: >= 0
    float4 bj = sboxg[g];
    float areaj = (bj.y - bj.x) * bj.w;
    for (int q = 0; q < 192; ++q) {
        int rie = (int)cr[q];
        if (rie == 0) continue;                  // empty slot
        int ri = rie - 1;
        if (ri >= rj) continue;                  // keeps only higher-conf suppressors
        float4 bi = cb[q];
        float inter_start = fmaxf(bi.x, bj.x);
        float inter_end   = fminf(bi.y, bj.y);
        float inter_len   = fmaxf(inter_end - inter_start, 0.0f);
        float inter_h     = fminf(bi.w, bj.w);
        float inter_area  = inter_len * inter_h;
        float areai       = (bi.y - bi.x) * bi.w;
        float union_area  = areai + areaj - inter_area;
        float iou         = inter_area / union_area;
        float peak_dist   = fabsf(bi.z - bj.z);
        float union_start = fminf(bi.x, bj.x);
        float union_end   = fmaxf(bi.y, bj.y);
        float union_dist  = fabsf(union_end - union_start);
        float piou        = iou - peak_dist / union_dist;
        if (piou > PIOU_THRESH) {
            if ((ri >> 7) == (rj >> 7)) {
                atomicOr(&meta[rj * 4 + ((ri >> 5) & 3)], 1u << (ri & 31));
            } else {
                int c = ri >> 7;
                u32 slot = atomicAdd(&echnk[c], 1u);
                if (slot < ECAP_CHUNK)
                    edges[(size_t)c * ECAP_CHUNK + slot] = ((u32)(ri & 127) << 16) | (u32)rj;
            }
        }
    }
}

// ---------------------------------------------------------------------------
// K4: EXACT greedy NMS with 128-RANK CHUNKS (verbatim proven R22, session
// best): waves 1-7 stage next round's 4 chunks (double-buffered), wave 0
// consumes with batch register prefetch + m==0 fast path; 128-wide ballot
// fixpoint (2 ranks/lane, rare path) + hang-guard; 256-edge cooperative
// sweeps; fused output tail; M = sum of bcnt. No setprio (R17 A/B).
// Parallel-gather variants (R23-25) measured null-to-negative; this serial
// structure is the floor.
// ---------------------------------------------------------------------------
__global__ void __launch_bounds__(NWAVE * 64) nmsout_kernel(
        const u32* __restrict__ bcnt, const u32* __restrict__ meta,
        const u32* __restrict__ edges, const u32* __restrict__ echnk,
        const float4* __restrict__ sbox, float4* __restrict__ out, int N) {
    __shared__ u32 alive[512];                   // 16384 bits, rank space
    __shared__ u32 sbuf[2][CPR][CHW];            // 128 KB double-buffered stage
    __shared__ u32 scnt[2][CPR];                 // staged edge counts
    __shared__ u32 mcnt;
    int tid = threadIdx.x;
    int w = tid >> 6, lane = tid & 63;

    // ---- M = sum over bins of (uncapped) valid counts ----
    if (tid < 64) {
        int lc = (int)bcnt[lane];
        lc += __shfl_xor(lc, 1);  lc += __shfl_xor(lc, 2);
        lc += __shfl_xor(lc, 4);  lc += __shfl_xor(lc, 8);
        lc += __shfl_xor(lc, 16); lc += __shfl_xor(lc, 32);
        if (lane == 0) mcnt = (u32)lc;
    }
    __syncthreads();
    int M = (int)mcnt;
    {
        int lo = tid * 32;
        alive[tid] = (M >= lo + 32) ? 0xFFFFFFFFu : ((M <= lo) ? 0u : ((1u << (M - lo)) - 1u));
    }
    int nchunk = (M + 127) >> 7;                 // 128-rank chunks
    int nround = (nchunk + CPR - 1) / CPR;
    __syncthreads();

#define STAGE(c, pb, k) { \
    int rr = ((c) << 7) + lane; \
    uint4 MT0 = ((const uint4*)meta)[rr]; \
    uint4 MT1 = ((const uint4*)meta)[rr + 64]; \
    u32 ec = echnk[c]; \
    const uint4* eg = (const uint4*)(edges + (size_t)(c) * ECAP_CHUNK); \
    uint4 EB[14]; \
    _Pragma("unroll") \
    for (int q = 0; q < 14; ++q) EB[q] = eg[q * 64 + lane]; \
    u32* sb = &sbuf[pb][k][0]; \
    ((uint4*)sb)[lane] = MT0; \
    ((uint4*)sb)[64 + lane] = MT1; \
    uint4* ed = (uint4*)(sb + 512); \
    _Pragma("unroll") \
    for (int q = 0; q < 14; ++q) ed[q * 64 + lane] = EB[q]; \
    if (lane == 0) scnt[pb][k] = ec; }

#define PROC_E(wd, idx, LIM) { \
    if ((int)(idx) < (LIM)) { \
        u32 sl = (wd) >> 16; u32 tg = (wd) & 0xFFFFu; \
        u64 ksel = (sl & 64) ? kept_hi : kept_lo; \
        if ((ksel >> (sl & 63)) & 1ull) atomicAnd(&alive[tg >> 5], ~(1u << (tg & 31))); } }

    if (nchunk > 0) {
        // prologue: waves 1-4 stage round 0's chunks into buffer 0
        if (w >= 1) {
            for (int k = w - 1; k < CPR; k += 7) {
                if (k < nchunk) STAGE(k, 0, k)
            }
        }
        __syncthreads();

        for (int rd = 0; rd < nround; ++rd) {
            int pb = rd & 1;
            if (w >= 1) {
                // stage round rd+1 into the other buffer
                int b2 = (rd + 1) * CPR;
                for (int k = w - 1; k < CPR; k += 7) {
                    int c = b2 + k;
                    if (c < nchunk) STAGE(c, pb ^ 1, k)
                }
            } else {
                // wave 0: batch-prefetch this round's meta halves / first edges / counts
                int nk = nchunk - rd * CPR; if (nk > CPR) nk = CPR;
                uint4 MT0s[CPR], MT1s[CPR], E0s[CPR]; u32 ECa[CPR];
#pragma unroll
                for (int k = 0; k < CPR; ++k) {
                    if (k < nk) {
                        const u32* sb = &sbuf[pb][k][0];
                        MT0s[k] = ((const uint4*)sb)[lane];
                        MT1s[k] = ((const uint4*)sb)[64 + lane];
                        E0s[k] = ((const uint4*)(sb + 512))[lane];
                        ECa[k] = scnt[pb][k];
                    }
                }
                // process chunks in rank order (alive chain stays serial)
#pragma unroll
                for (int k = 0; k < CPR; ++k) {
                    if (k < nk) {
                        int c = rd * CPR + k;
                        int base = c << 7;
                        const u32* sb = &sbuf[pb][k][0];
                        uint4 MT0 = MT0s[k], MT1 = MT1s[k];
                        u64 av_lo = ((u64)alive[(base >> 5) + 1] << 32) | (u64)alive[base >> 5];
                        u64 av_hi = ((u64)alive[(base >> 5) + 3] << 32) | (u64)alive[(base >> 5) + 2];
                        u64 kept_lo, kept_hi;
                        u32 anym = MT0.x | MT0.y | MT0.z | MT0.w | MT1.x | MT1.y | MT1.z | MT1.w;
                        if (__ballot(anym != 0u) == 0ull) {
                            kept_lo = av_lo; kept_hi = av_hi;    // no in-chunk deps (common)
                        } else {
                            u64 m0_lo = MT0.x | ((u64)MT0.y << 32), m0_hi = MT0.z | ((u64)MT0.w << 32);
                            u64 m1_lo = MT1.x | ((u64)MT1.y << 32), m1_hi = MT1.z | ((u64)MT1.w << 32);
                            u64 undec_lo = av_lo, undec_hi = av_hi;
                            kept_lo = 0ull; kept_hi = 0ull;
                            while (undec_lo | undec_hi) {
                                bool iam0 = (undec_lo >> lane) & 1ull;
                                bool bad0 = ((m0_lo & kept_lo) | (m0_hi & kept_hi)) != 0ull;
                                bool rdy0 = ((m0_lo & undec_lo) | (m0_hi & undec_hi)) == 0ull;
                                bool iam1 = (undec_hi >> lane) & 1ull;
                                bool bad1 = ((m1_lo & kept_lo) | (m1_hi & kept_hi)) != 0ull;
                                bool rdy1 = ((m1_lo & undec_lo) | (m1_hi & undec_hi)) == 0ull;
                                u64 nk_lo = __ballot(iam0 && !bad0 && rdy0);
                                u64 nr_lo = __ballot(iam0 && bad0);
                                u64 nk_hi = __ballot(iam1 && !bad1 && rdy1);
                                u64 nr_hi = __ballot(iam1 && bad1);
                                u64 pl = nk_lo | nr_lo, ph = nk_hi | nr_hi;
                                if ((pl | ph) == 0ull) {         // hang insurance (dead on valid data)
                                    if (undec_lo) { pl = undec_lo & (~undec_lo + 1ull); nk_lo = pl; }
                                    else          { ph = undec_hi & (~undec_hi + 1ull); nk_hi = ph; }
                                }
                                kept_lo |= nk_lo; kept_hi |= nk_hi;
                                undec_lo &= ~pl;  undec_hi &= ~ph;
                            }
                        }
                        if (lane < 4) {
                            u32 word = (lane == 0) ? (u32)kept_lo :
                                       (lane == 1) ? (u32)(kept_lo >> 32) :
                                       (lane == 2) ? (u32)kept_hi : (u32)(kept_hi >> 32);
                            alive[(base >> 5) + lane] = word;
                        }

                        int EC = min((int)ECa[k], ECAP_CHUNK);
                        int ECl = min(EC, ESTG);
                        const uint4* ed = (const uint4*)(sb + 512);
                        if (ECl > 0) {                       // it = 0 from prefetch
                            uint4 E = E0s[k];
                            int e0 = lane * 4;
                            PROC_E(E.x, e0,     ECl)
                            PROC_E(E.y, e0 + 1, ECl)
                            PROC_E(E.z, e0 + 2, ECl)
                            PROC_E(E.w, e0 + 3, ECl)
                        }
                        for (int it = 1; it * 256 < ECl; ++it) {   // uniform bound
                            uint4 E = ed[it * 64 + lane];
                            int e0 = it * 256 + lane * 4;
                            PROC_E(E.x, e0,     ECl)
                            PROC_E(E.y, e0 + 1, ECl)
                            PROC_E(E.z, e0 + 2, ECl)
                            PROC_E(E.w, e0 + 3, ECl)
                        }
                        if (EC > ESTG) {                     // rare coalesced tail
                            const uint4* eg = (const uint4*)(edges + (size_t)c * ECAP_CHUNK);
                            for (int eb = ESTG; eb < EC; eb += 256) {
                                uint4 E = eg[(eb >> 2) + lane];
                                int e0 = eb + lane * 4;
                                PROC_E(E.x, e0,     EC)
                                PROC_E(E.y, e0 + 1, EC)
                                PROC_E(E.z, e0 + 2, EC)
                                PROC_E(E.w, e0 + 3, EC)
                            }
                        }
                    }
                }
            }
            __syncthreads();                     // staging done + buffer handoff
        }
    }

    // fused output: all 8 waves stream the result (alive is final)
    for (int r = tid; r < N; r += NWAVE * 64) {
        if (r < M) {
            float kf = (float)((alive[r >> 5] >> (r & 31)) & 1u);
            float4 v = sbox[r];
            out[r] = make_float4(v.x * kf, v.y * kf, v.z * kf, v.w * kf);
        } else {
            out[r] = make_float4(0.0f, 0.0f, 0.0f, 0.0f);
        }
    }
#undef STAGE
#undef PROC_E
}

// ---------------------------------------------------------------------------
extern "C" void kernel_launch(void* const* d_in, const int* in_sizes, int n_in,
                              void* d_out, int out_size, void* d_ws, size_t ws_size,
                              hipStream_t stream) {
    const float* in = (const float*)d_in[0];
    int N = in_sizes[0] / 5;          // 16384
    int nchunk_max = N / 128;         // 128

    char* ws = (char*)d_ws;
    size_t off = 0;
    u32* hist    = (u32*)(ws + off); off += (size_t)NBKT * 4;         // 8 KB (memset'd)
    u32* bcnt    = (u32*)(ws + off); off += (size_t)NBIN * 4;         // 256 B
    u32* echnk   = (u32*)(ws + off); off += 256 * 4;                  // 1 KB (128 used)
    u16* grankg  = (u16*)(ws + off); off += (size_t)N * 2;            // 32 KB
    off = (off + 15) & ~(size_t)15;
    u32* meta    = (u32*)(ws + off); off += (size_t)N * 16;           // 256 KB
    u64* mem     = (u64*)(ws + off); off += (size_t)NBKT * BCAP * 8;  // 1 MB
    float4* sbox  = (float4*)(ws + off); off += (size_t)N * 16;       // 256 KB
    float4* sboxg = (float4*)(ws + off); off += (size_t)N * 16;       // 256 KB
    u32* edges   = (u32*)(ws + off);  off += (size_t)nchunk_max * ECAP_CHUNK * 4;  // 6 MB

    hipMemsetAsync(hist, 0, (size_t)NBKT * 4, stream);

    hist_kernel<<<N / 256, 256, 0, stream>>>(in, hist, mem, meta, echnk, bcnt, grankg, N);
    rankscat_kernel<<<N / 256, 256, 0, stream>>>(in, hist, mem, sbox, bcnt, grankg, sboxg, N);
    mask_pm1_kernel<<<dim3(NBIN, 4), 256, 0, stream>>>(sboxg, grankg, bcnt, meta, edges, echnk);
    nmsout_kernel<<<1, NWAVE * 64, 0, stream>>>(bcnt, meta, edges, echnk, sbox, (float4*)d_out, N);
}